// Round 7
// baseline (547.154 us; speedup 1.0000x reference)
//
#include <hip/hip_runtime.h>
#include <hip/hip_bf16.h>
#include <math.h>

// Problem constants (fixed by setup_inputs): N=2048, D=512, K=65536
#define N_ROWS 2048
#define D_DIM  512
#define K_NEG  65536
#define INV_T  5.0f   // 1/0.2
#define NC     4      // colBlocks processed per block (epilogue amortization)
#define NT     (NC * 16)   // flat pipeline iterations: NC colBlocks x 16 kt

typedef __bf16 bf16x8 __attribute__((ext_vector_type(8)));
typedef float  f32x4  __attribute__((ext_vector_type(4)));

__device__ __forceinline__ void gload_lds16(const __bf16* g, __bf16* l) {
    __builtin_amdgcn_global_load_lds(
        (const __attribute__((address_space(1))) void*)g,
        (__attribute__((address_space(3))) void*)l, 16, 0, 0);
}

// ---------------------------------------------------------------------------
// Kernel 1 (merged preps), with NORM FOLDING:
//  blocks [0, 512):    Abf = bf16(query * (5/||q||)), lpos exact, rowsum=exp(lpos)
//  blocks [512, ...):  Bbf = bf16(queue / ||u||)
// so the GEMM's accumulator IS the logit — no scales inside the K-loop.
// ---------------------------------------------------------------------------
__global__ __launch_bounds__(256) void prep_all_kernel(
    const float* __restrict__ query, const float* __restrict__ keys,
    const float* __restrict__ queue,
    __bf16* __restrict__ Abf, __bf16* __restrict__ Bbf,
    float* __restrict__ lpos, float* __restrict__ rowsum) {
    const int lane = threadIdx.x & 63;
    if (blockIdx.x < N_ROWS / 4) {
        const int row = blockIdx.x * 4 + (threadIdx.x >> 6);
        const float4* qv = reinterpret_cast<const float4*>(query + (size_t)row * D_DIM) + lane * 2;
        const float4* kv = reinterpret_cast<const float4*>(keys  + (size_t)row * D_DIM) + lane * 2;
        float4 q0 = qv[0], q1 = qv[1];
        float4 k0 = kv[0], k1 = kv[1];
        float ssq = q0.x*q0.x + q0.y*q0.y + q0.z*q0.z + q0.w*q0.w
                  + q1.x*q1.x + q1.y*q1.y + q1.z*q1.z + q1.w*q1.w;
        float ssk = k0.x*k0.x + k0.y*k0.y + k0.z*k0.z + k0.w*k0.w
                  + k1.x*k1.x + k1.y*k1.y + k1.z*k1.z + k1.w*k1.w;
        float dot = q0.x*k0.x + q0.y*k0.y + q0.z*k0.z + q0.w*k0.w
                  + q1.x*k1.x + q1.y*k1.y + q1.z*k1.z + q1.w*k1.w;
#pragma unroll
        for (int off = 32; off > 0; off >>= 1) {
            ssq += __shfl_xor(ssq, off, 64);
            ssk += __shfl_xor(ssk, off, 64);
            dot += __shfl_xor(dot, off, 64);
        }
        const float qn = sqrtf(ssq), kn = sqrtf(ssk);
        const float aS = INV_T / fmaxf(qn, 1e-8f);   // folded scale
        bf16x8 o;
        o[0] = (__bf16)(q0.x*aS); o[1] = (__bf16)(q0.y*aS);
        o[2] = (__bf16)(q0.z*aS); o[3] = (__bf16)(q0.w*aS);
        o[4] = (__bf16)(q1.x*aS); o[5] = (__bf16)(q1.y*aS);
        o[6] = (__bf16)(q1.z*aS); o[7] = (__bf16)(q1.w*aS);
        reinterpret_cast<bf16x8*>(Abf + (size_t)row * D_DIM)[lane] = o;
        if (lane == 0) {
            float lp = dot / fmaxf(qn * kn, 1e-8f) * INV_T;   // exact fp32 path
            lpos[row]   = lp;
            rowsum[row] = __expf(lp);   // positive-logit term; also inits accumulator
        }
    } else {
        const int row = (blockIdx.x - N_ROWS / 4) * 4 + (threadIdx.x >> 6);
        const float4* uv = reinterpret_cast<const float4*>(queue + (size_t)row * D_DIM) + lane * 2;
        float4 u0 = uv[0], u1 = uv[1];
        float ss = u0.x*u0.x + u0.y*u0.y + u0.z*u0.z + u0.w*u0.w
                 + u1.x*u1.x + u1.y*u1.y + u1.z*u1.z + u1.w*u1.w;
#pragma unroll
        for (int off = 32; off > 0; off >>= 1) ss += __shfl_xor(ss, off, 64);
        const float uS = 1.0f / fmaxf(sqrtf(ss), 1e-8f);     // folded scale
        bf16x8 o;
        o[0] = (__bf16)(u0.x*uS); o[1] = (__bf16)(u0.y*uS);
        o[2] = (__bf16)(u0.z*uS); o[3] = (__bf16)(u0.w*uS);
        o[4] = (__bf16)(u1.x*uS); o[5] = (__bf16)(u1.y*uS);
        o[6] = (__bf16)(u1.z*uS); o[7] = (__bf16)(u1.w*uS);
        reinterpret_cast<bf16x8*>(Bbf + (size_t)row * D_DIM)[lane] = o;
    }
}

// ---------------------------------------------------------------------------
// Kernel 2: NT-GEMM with fused exp-rowsum.  Inputs pre-normalized: acc IS
// the logit.  Round-7 (= R6 with the compile fix): distance-2 prefetch,
// 3 LDS buffers, __builtin_amdgcn_s_waitcnt + __builtin_amdgcn_s_barrier
// (no "memory" clobber -> no accumulator spill, unlike R4/R5's asm).
// The builtin needs a front-end integer constant, so the final iteration
// (vmcnt(0)) is PEELED out of the unrolled loop instead of selected by a
// ternary on t.
// waitcnt imm encoding (gfx9): vmcnt[3:0]=b3:0, expcnt=b6:4, lgkmcnt=b11:8.
//   0xF74 = vmcnt(4) only;  0xF70 = vmcnt(0) only.
// vmcnt accounting (only stage loads touch vmcnt): at barrier(t) stages t
// and t+1 are outstanding (8 loads) -> vmcnt(4) drains exactly stage t.
// Peeled last iteration has only its own 4 outstanding -> vmcnt(0).
// ---------------------------------------------------------------------------
__global__ __launch_bounds__(256, 3) void gemm_exp_kernel(
    const __bf16* __restrict__ A, const __bf16* __restrict__ B,
    float* __restrict__ rowsum) {
    __shared__ __bf16 sAB[3][2][4096];   // [buf][A/B][128x32]  48 KB
    const int tid  = threadIdx.x;
    const int wave = tid >> 6, lane = tid & 63;
    const int rowBlock = blockIdx.x;   // 0..15  (fastest -> B-tile temporal locality)
    const int colGroup = blockIdx.y;   // 0..127 (NC=4 colBlocks each)

    const int wm = wave >> 1, wn = wave & 1;
    const int q4 = lane >> 4, m16 = lane & 15;

    // staging lane map: lane = r4*4 + c2; LDS slot (r4,c2) <- global chunk
    // g = c2 ^ ((r4>>1)&3)  (source-address swizzle; dest is uniform+lane*16)
    const int r4 = lane >> 2, c2 = lane & 3;
    const int gsw = c2 ^ ((r4 >> 1) & 3);
    const int j0 = wave, j1 = wave + 4;          // 16-row chunks this wave stages
    const __bf16* gA  = A + (((size_t)(rowBlock * 128 + r4)) << 9) + (gsw << 3);
    const __bf16* gB0 = B + (((size_t)(colGroup * NC * 128 + r4)) << 9) + (gsw << 3);
    const int rsw = (q4 ^ ((m16 >> 1) & 3)) << 3;   // read-side swizzled chunk offset

    float srow[4][4] = {{0.f,0.f,0.f,0.f},{0.f,0.f,0.f,0.f},
                        {0.f,0.f,0.f,0.f},{0.f,0.f,0.f,0.f}};
    f32x4 acc[4][4] = {};

#define STAGE(T, BUF) do {                                                        \
        const int cb_ = (T) >> 4, kof_ = ((T) & 15) * 32;                         \
        const __bf16* gBc_ = gB0 + ((size_t)cb_ << 16);                           \
        __bf16* dA_ = &sAB[(BUF)][0][0];                                          \
        __bf16* dB_ = &sAB[(BUF)][1][0];                                          \
        gload_lds16(gA  + (size_t)j0 * 16 * D_DIM + kof_, &dA_[j0 * 512]);        \
        gload_lds16(gA  + (size_t)j1 * 16 * D_DIM + kof_, &dA_[j1 * 512]);        \
        gload_lds16(gBc_ + (size_t)j0 * 16 * D_DIM + kof_, &dB_[j0 * 512]);       \
        gload_lds16(gBc_ + (size_t)j1 * 16 * D_DIM + kof_, &dB_[j1 * 512]);       \
    } while (0)

    // one t-iteration's compute (no barrier), BUF = t%3 must be constant
#define COMPUTE(T, BUF) do {                                                      \
        const __bf16* bA_ = &sAB[(BUF)][0][0];                                    \
        const __bf16* bB_ = &sAB[(BUF)][1][0];                                    \
        bf16x8 af[4], bq[4];                                                      \
        _Pragma("unroll")                                                         \
        for (int i = 0; i < 4; ++i)                                               \
            af[i] = *reinterpret_cast<const bf16x8*>(                             \
                &bA_[(wm * 64 + i * 16 + m16) * 32 + rsw]);                       \
        _Pragma("unroll")                                                         \
        for (int j = 0; j < 4; ++j)                                               \
            bq[j] = *reinterpret_cast<const bf16x8*>(                             \
                &bB_[(wn * 64 + j * 16 + m16) * 32 + rsw]);                       \
        _Pragma("unroll")                                                         \
        for (int i = 0; i < 4; ++i)                                               \
            _Pragma("unroll")                                                     \
            for (int j = 0; j < 4; ++j)                                           \
                acc[i][j] = __builtin_amdgcn_mfma_f32_16x16x32_bf16(              \
                    af[i], bq[j], acc[i][j], 0, 0, 0);                            \
    } while (0)

    // colBlock epilogue: acc IS the logit -> exp, accumulate, reset
#define EPILOGUE() do {                                                           \
        _Pragma("unroll")                                                         \
        for (int i = 0; i < 4; ++i)                                               \
            _Pragma("unroll")                                                     \
            for (int r = 0; r < 4; ++r) {                                         \
                float s = 0.f;                                                    \
                _Pragma("unroll")                                                 \
                for (int j = 0; j < 4; ++j)                                       \
                    s += __expf(acc[i][j][r]);                                    \
                srow[i][r] += s;                                                  \
            }                                                                     \
        _Pragma("unroll")                                                         \
        for (int i = 0; i < 4; ++i)                                               \
            _Pragma("unroll")                                                     \
            for (int j = 0; j < 4; ++j)                                           \
                acc[i][j] = f32x4{0.f, 0.f, 0.f, 0.f};                            \
    } while (0)

    STAGE(0, 0);
    STAGE(1, 1);

#pragma unroll
    for (int t = 0; t < NT - 1; ++t) {
        // Drain ONLY stage t (issued 2 iterations ago); keep stage t+1 in flight.
        __builtin_amdgcn_s_waitcnt(0xF74);   // vmcnt(4)
        __builtin_amdgcn_s_barrier();
        if (t + 2 < NT) STAGE(t + 2, (t + 2) % 3);
        COMPUTE(t, t % 3);
        if ((t & 15) == 15) EPILOGUE();
    }
    // peeled final iteration t = NT-1: only its own 4 loads outstanding
    __builtin_amdgcn_s_waitcnt(0xF70);       // vmcnt(0)
    __builtin_amdgcn_s_barrier();
    COMPUTE(NT - 1, (NT - 1) % 3);
    EPILOGUE();

#undef STAGE
#undef COMPUTE
#undef EPILOGUE

    // one shuffle-reduce + atomic per row per block
#pragma unroll
    for (int i = 0; i < 4; ++i)
#pragma unroll
        for (int r = 0; r < 4; ++r) {
            float s = srow[i][r];
#pragma unroll
            for (int off = 1; off < 16; off <<= 1)
                s += __shfl_xor(s, off, 64);
            if (m16 == 0) {
                const int grow = rowBlock * 128 + wm * 64 + i * 16 + q4 * 4 + r;
                atomicAdd(&rowsum[grow], s);
            }
        }
}

// ---------------------------------------------------------------------------
// Kernel 3: loss = mean(log(rowsum) - lpos)
// ---------------------------------------------------------------------------
__global__ __launch_bounds__(256) void finalize_kernel(
    const float* __restrict__ rowsum, const float* __restrict__ lpos,
    float* __restrict__ out) {
    const int tid = threadIdx.x;
    float acc = 0.f;
    for (int n = tid; n < N_ROWS; n += 256)
        acc += __logf(rowsum[n]) - lpos[n];
#pragma unroll
    for (int off = 32; off > 0; off >>= 1) acc += __shfl_xor(acc, off, 64);
    __shared__ float red[4];
    if ((tid & 63) == 0) red[tid >> 6] = acc;
    __syncthreads();
    if (tid == 0) out[0] = (red[0] + red[1] + red[2] + red[3]) * (1.0f / (float)N_ROWS);
}

extern "C" void kernel_launch(void* const* d_in, const int* in_sizes, int n_in,
                              void* d_out, int out_size, void* d_ws, size_t ws_size,
                              hipStream_t stream) {
    const float* query = (const float*)d_in[0];
    const float* keys  = (const float*)d_in[1];
    const float* queue = (const float*)d_in[2];

    char* ws = (char*)d_ws;
    __bf16* Abf = (__bf16*)ws;  ws += (size_t)N_ROWS * D_DIM * sizeof(__bf16);   // 2 MB
    __bf16* Bbf = (__bf16*)ws;  ws += (size_t)K_NEG  * D_DIM * sizeof(__bf16);   // 64 MB
    float*  lpos = (float*)ws;  ws += (size_t)N_ROWS * sizeof(float);
    float*  rsum = (float*)ws;  ws += (size_t)N_ROWS * sizeof(float);

    prep_all_kernel<<<N_ROWS / 4 + K_NEG / 4, 256, 0, stream>>>(
        query, keys, queue, Abf, Bbf, lpos, rsum);
    gemm_exp_kernel<<<dim3(N_ROWS / 128, K_NEG / 128 / NC), 256, 0, stream>>>(
        Abf, Bbf, rsum);
    finalize_kernel<<<1, 256, 0, stream>>>(rsum, lpos, (float*)d_out);
}

// Round 8
// 519.662 us; speedup vs baseline: 1.0529x; 1.0529x over previous
//
#include <hip/hip_runtime.h>
#include <hip/hip_bf16.h>
#include <math.h>

// Problem constants (fixed by setup_inputs): N=2048, D=512, K=65536
#define N_ROWS 2048
#define D_DIM  512
#define K_NEG  65536
#define INV_T  5.0f   // 1/0.2
#define NC     4      // colBlocks processed per block (epilogue amortization)
#define NT     (NC * 16)   // flat pipeline iterations: NC colBlocks x 16 kt

typedef __bf16 bf16x8 __attribute__((ext_vector_type(8)));
typedef float  f32x4  __attribute__((ext_vector_type(4)));

__device__ __forceinline__ void gload_lds16(const __bf16* g, __bf16* l) {
    __builtin_amdgcn_global_load_lds(
        (const __attribute__((address_space(1))) void*)g,
        (__attribute__((address_space(3))) void*)l, 16, 0, 0);
}

// ---------------------------------------------------------------------------
// Kernel 1 (merged preps), with NORM FOLDING:
//  blocks [0, 512):    Abf = bf16(query * (5/||q||)), lpos exact, rowsum=exp(lpos)
//  blocks [512, ...):  Bbf = bf16(queue / ||u||)
// so the GEMM's accumulator IS the logit — no scales inside the K-loop.
// ---------------------------------------------------------------------------
__global__ __launch_bounds__(256) void prep_all_kernel(
    const float* __restrict__ query, const float* __restrict__ keys,
    const float* __restrict__ queue,
    __bf16* __restrict__ Abf, __bf16* __restrict__ Bbf,
    float* __restrict__ lpos, float* __restrict__ rowsum) {
    const int lane = threadIdx.x & 63;
    if (blockIdx.x < N_ROWS / 4) {
        const int row = blockIdx.x * 4 + (threadIdx.x >> 6);
        const float4* qv = reinterpret_cast<const float4*>(query + (size_t)row * D_DIM) + lane * 2;
        const float4* kv = reinterpret_cast<const float4*>(keys  + (size_t)row * D_DIM) + lane * 2;
        float4 q0 = qv[0], q1 = qv[1];
        float4 k0 = kv[0], k1 = kv[1];
        float ssq = q0.x*q0.x + q0.y*q0.y + q0.z*q0.z + q0.w*q0.w
                  + q1.x*q1.x + q1.y*q1.y + q1.z*q1.z + q1.w*q1.w;
        float ssk = k0.x*k0.x + k0.y*k0.y + k0.z*k0.z + k0.w*k0.w
                  + k1.x*k1.x + k1.y*k1.y + k1.z*k1.z + k1.w*k1.w;
        float dot = q0.x*k0.x + q0.y*k0.y + q0.z*k0.z + q0.w*k0.w
                  + q1.x*k1.x + q1.y*k1.y + q1.z*k1.z + q1.w*k1.w;
#pragma unroll
        for (int off = 32; off > 0; off >>= 1) {
            ssq += __shfl_xor(ssq, off, 64);
            ssk += __shfl_xor(ssk, off, 64);
            dot += __shfl_xor(dot, off, 64);
        }
        const float qn = sqrtf(ssq), kn = sqrtf(ssk);
        const float aS = INV_T / fmaxf(qn, 1e-8f);   // folded scale
        bf16x8 o;
        o[0] = (__bf16)(q0.x*aS); o[1] = (__bf16)(q0.y*aS);
        o[2] = (__bf16)(q0.z*aS); o[3] = (__bf16)(q0.w*aS);
        o[4] = (__bf16)(q1.x*aS); o[5] = (__bf16)(q1.y*aS);
        o[6] = (__bf16)(q1.z*aS); o[7] = (__bf16)(q1.w*aS);
        reinterpret_cast<bf16x8*>(Abf + (size_t)row * D_DIM)[lane] = o;
        if (lane == 0) {
            float lp = dot / fmaxf(qn * kn, 1e-8f) * INV_T;   // exact fp32 path
            lpos[row]   = lp;
            rowsum[row] = __expf(lp);   // positive-logit term; also inits accumulator
        }
    } else {
        const int row = (blockIdx.x - N_ROWS / 4) * 4 + (threadIdx.x >> 6);
        const float4* uv = reinterpret_cast<const float4*>(queue + (size_t)row * D_DIM) + lane * 2;
        float4 u0 = uv[0], u1 = uv[1];
        float ss = u0.x*u0.x + u0.y*u0.y + u0.z*u0.z + u0.w*u0.w
                 + u1.x*u1.x + u1.y*u1.y + u1.z*u1.z + u1.w*u1.w;
#pragma unroll
        for (int off = 32; off > 0; off >>= 1) ss += __shfl_xor(ss, off, 64);
        const float uS = 1.0f / fmaxf(sqrtf(ss), 1e-8f);     // folded scale
        bf16x8 o;
        o[0] = (__bf16)(u0.x*uS); o[1] = (__bf16)(u0.y*uS);
        o[2] = (__bf16)(u0.z*uS); o[3] = (__bf16)(u0.w*uS);
        o[4] = (__bf16)(u1.x*uS); o[5] = (__bf16)(u1.y*uS);
        o[6] = (__bf16)(u1.z*uS); o[7] = (__bf16)(u1.w*uS);
        reinterpret_cast<bf16x8*>(Bbf + (size_t)row * D_DIM)[lane] = o;
    }
}

// ---------------------------------------------------------------------------
// Kernel 2: NT-GEMM with fused exp-rowsum.  Inputs pre-normalized: acc IS
// the logit.
// Round-8: REVERT to the verified R3 pipeline (2 LDS buffers, distance-1
// prefetch, __syncthreads, fully-unrolled flat t-loop) — measured 196 µs,
// WRITE 8 MB, VGPR 72.  All distance-2 / custom-barrier variants (R4/R5/R7,
// asm AND builtin) triggered a ~500 MB scratch-write anomaly and ~360 µs;
// that lever is retired.  Norm folding kept from R4: the t-loop's only VMEM
// is the 4 stage loads, and the colBlock epilogue is exp(acc) with no loads.
// Frozen wins: source-address XOR swizzle (bank conflicts measured 0),
// NC=4 colBlocks/block, rowBlock-fastest grid (B-tile L2 locality).
// ---------------------------------------------------------------------------
__global__ __launch_bounds__(256, 3) void gemm_exp_kernel(
    const __bf16* __restrict__ A, const __bf16* __restrict__ B,
    float* __restrict__ rowsum) {
    __shared__ __bf16 sA[2 * 4096];
    __shared__ __bf16 sB[2 * 4096];
    const int tid  = threadIdx.x;
    const int wave = tid >> 6, lane = tid & 63;
    const int rowBlock = blockIdx.x;   // 0..15  (fastest -> B-tile temporal locality)
    const int colGroup = blockIdx.y;   // 0..127 (NC=4 colBlocks each)

    const int wm = wave >> 1, wn = wave & 1;
    const int q4 = lane >> 4, m16 = lane & 15;

    // staging lane map: lane = r4*4 + c2; LDS slot (r4,c2) <- global chunk
    // g = c2 ^ ((r4>>1)&3)  (source-address swizzle; dest is uniform+lane*16)
    const int r4 = lane >> 2, c2 = lane & 3;
    const int gsw = c2 ^ ((r4 >> 1) & 3);
    const int j0 = wave, j1 = wave + 4;          // 16-row chunks this wave stages
    const __bf16* gA  = A + (((size_t)(rowBlock * 128 + r4)) << 9) + (gsw << 3);
    const __bf16* gB0 = B + (((size_t)(colGroup * NC * 128 + r4)) << 9) + (gsw << 3);
    const int rsw = (q4 ^ ((m16 >> 1) & 3)) << 3;   // read-side swizzled chunk offset

    float srow[4][4] = {{0.f,0.f,0.f,0.f},{0.f,0.f,0.f,0.f},
                        {0.f,0.f,0.f,0.f},{0.f,0.f,0.f,0.f}};
    f32x4 acc[4][4] = {};

#define STAGE(T, BUF) do {                                                        \
        const int cb_ = (T) >> 4, kof_ = ((T) & 15) * 32;                         \
        const __bf16* gBc_ = gB0 + ((size_t)cb_ << 16);                           \
        __bf16* dA_ = &sA[(BUF) * 4096];                                          \
        __bf16* dB_ = &sB[(BUF) * 4096];                                          \
        gload_lds16(gA  + (size_t)j0 * 16 * D_DIM + kof_, &dA_[j0 * 512]);        \
        gload_lds16(gA  + (size_t)j1 * 16 * D_DIM + kof_, &dA_[j1 * 512]);        \
        gload_lds16(gBc_ + (size_t)j0 * 16 * D_DIM + kof_, &dB_[j0 * 512]);       \
        gload_lds16(gBc_ + (size_t)j1 * 16 * D_DIM + kof_, &dB_[j1 * 512]);       \
    } while (0)

    STAGE(0, 0);

#pragma unroll
    for (int t = 0; t < NT; ++t) {
        const int cur = t & 1;
        __syncthreads();                  // drains loads(t); protects buf cur^1 reuse
        if (t + 1 < NT) STAGE(t + 1, cur ^ 1);

        const __bf16* bA = &sA[cur * 4096];
        const __bf16* bB = &sB[cur * 4096];
        bf16x8 af[4], bq[4];
#pragma unroll
        for (int i = 0; i < 4; ++i)
            af[i] = *reinterpret_cast<const bf16x8*>(&bA[(wm * 64 + i * 16 + m16) * 32 + rsw]);
#pragma unroll
        for (int j = 0; j < 4; ++j)
            bq[j] = *reinterpret_cast<const bf16x8*>(&bB[(wn * 64 + j * 16 + m16) * 32 + rsw]);
#pragma unroll
        for (int i = 0; i < 4; ++i)
#pragma unroll
            for (int j = 0; j < 4; ++j)
                acc[i][j] = __builtin_amdgcn_mfma_f32_16x16x32_bf16(af[i], bq[j], acc[i][j], 0, 0, 0);

        if ((t & 15) == 15) {   // colBlock done: acc IS the logit -> exp, accumulate, reset
#pragma unroll
            for (int i = 0; i < 4; ++i)
#pragma unroll
                for (int r = 0; r < 4; ++r) {
                    float s = 0.f;
#pragma unroll
                    for (int j = 0; j < 4; ++j)
                        s += __expf(acc[i][j][r]);
                    srow[i][r] += s;
                }
#pragma unroll
            for (int i = 0; i < 4; ++i)
#pragma unroll
                for (int j = 0; j < 4; ++j)
                    acc[i][j] = f32x4{0.f, 0.f, 0.f, 0.f};
        }
    }
#undef STAGE

    // one shuffle-reduce + atomic per row per block
#pragma unroll
    for (int i = 0; i < 4; ++i)
#pragma unroll
        for (int r = 0; r < 4; ++r) {
            float s = srow[i][r];
#pragma unroll
            for (int off = 1; off < 16; off <<= 1)
                s += __shfl_xor(s, off, 64);
            if (m16 == 0) {
                const int grow = rowBlock * 128 + wm * 64 + i * 16 + q4 * 4 + r;
                atomicAdd(&rowsum[grow], s);
            }
        }
}

// ---------------------------------------------------------------------------
// Kernel 3: loss = mean(log(rowsum) - lpos)
// ---------------------------------------------------------------------------
__global__ __launch_bounds__(256) void finalize_kernel(
    const float* __restrict__ rowsum, const float* __restrict__ lpos,
    float* __restrict__ out) {
    const int tid = threadIdx.x;
    float acc = 0.f;
    for (int n = tid; n < N_ROWS; n += 256)
        acc += __logf(rowsum[n]) - lpos[n];
#pragma unroll
    for (int off = 32; off > 0; off >>= 1) acc += __shfl_xor(acc, off, 64);
    __shared__ float red[4];
    if ((tid & 63) == 0) red[tid >> 6] = acc;
    __syncthreads();
    if (tid == 0) out[0] = (red[0] + red[1] + red[2] + red[3]) * (1.0f / (float)N_ROWS);
}

extern "C" void kernel_launch(void* const* d_in, const int* in_sizes, int n_in,
                              void* d_out, int out_size, void* d_ws, size_t ws_size,
                              hipStream_t stream) {
    const float* query = (const float*)d_in[0];
    const float* keys  = (const float*)d_in[1];
    const float* queue = (const float*)d_in[2];

    char* ws = (char*)d_ws;
    __bf16* Abf = (__bf16*)ws;  ws += (size_t)N_ROWS * D_DIM * sizeof(__bf16);   // 2 MB
    __bf16* Bbf = (__bf16*)ws;  ws += (size_t)K_NEG  * D_DIM * sizeof(__bf16);   // 64 MB
    float*  lpos = (float*)ws;  ws += (size_t)N_ROWS * sizeof(float);
    float*  rsum = (float*)ws;  ws += (size_t)N_ROWS * sizeof(float);

    prep_all_kernel<<<N_ROWS / 4 + K_NEG / 4, 256, 0, stream>>>(
        query, keys, queue, Abf, Bbf, lpos, rsum);
    gemm_exp_kernel<<<dim3(N_ROWS / 128, K_NEG / 128 / NC), 256, 0, stream>>>(
        Abf, Bbf, rsum);
    finalize_kernel<<<1, 256, 0, stream>>>(rsum, lpos, (float*)d_out);
}